// Round 1
// baseline (621.723 us; speedup 1.0000x reference)
//
#include <hip/hip_runtime.h>
#include <stdint.h>

typedef __bf16 bf16;
typedef __bf16 bf16x4 __attribute__((ext_vector_type(4)));
typedef __bf16 bf16x8 __attribute__((ext_vector_type(8)));
typedef float  f32x4  __attribute__((ext_vector_type(4)));

#define B_DIM 16384
#define H_DIM 1024
#define K_DIM 2048   // I + H concatenated

// ---- async global->LDS, 16B per lane (m97: the single biggest step, 517->874 TF) ----
__device__ __forceinline__ void g2l16(const void* g, void* l) {
    __builtin_amdgcn_global_load_lds(
        (const __attribute__((address_space(1))) void*)g,
        (__attribute__((address_space(3))) void*)l,
        16, 0, 0);
}

__device__ __forceinline__ float sigm_fast(float x) {
    x = fminf(fmaxf(x, -40.f), 40.f);
    float e = __builtin_amdgcn_exp2f(-1.4426950408889634f * x);
    return __builtin_amdgcn_rcpf(1.0f + e);
}
__device__ __forceinline__ float tanh_fast(float x) {
    x = fminf(fmaxf(x, -40.f), 40.f);
    float e = __builtin_amdgcn_exp2f(-2.8853900817779268f * x);   // exp(-2x)
    return (1.0f - e) * __builtin_amdgcn_rcpf(1.0f + e);
}

// ---- convert x,h_prev (fp32) -> U bf16 [B, 2048]: U[b,0:1024]=x[b], U[b,1024:2048]=h_prev[b]
__global__ __launch_bounds__(256) void cvt_xh(const float* __restrict__ x,
                                              const float* __restrict__ h,
                                              bf16* __restrict__ U) {
    int t = blockIdx.x * 256 + threadIdx.x;    // B*256 threads, 4 elems each side
    int b = t >> 8;
    int j = (t & 255) << 2;
    float4 xv = *(const float4*)(x + ((size_t)b << 10) + j);
    float4 hv = *(const float4*)(h + ((size_t)b << 10) + j);
    bf16x4 xo = { (bf16)xv.x, (bf16)xv.y, (bf16)xv.z, (bf16)xv.w };
    bf16x4 ho = { (bf16)hv.x, (bf16)hv.y, (bf16)hv.z, (bf16)hv.w };
    *(bf16x4*)(U + ((size_t)b << 11) + j)        = xo;
    *(bf16x4*)(U + ((size_t)b << 11) + 1024 + j) = ho;
}

// ---- convert Wx,Rh -> W bf16 [4096, 2048] (row g*1024+h = [Wx[g,h,:] | Rh[g,h,:]]); bb = bx+bh
__global__ __launch_bounds__(256) void cvt_w(const float* __restrict__ Wx,
                                             const float* __restrict__ Rh,
                                             const float* __restrict__ bx,
                                             const float* __restrict__ bh,
                                             bf16* __restrict__ W,
                                             float* __restrict__ bb) {
    int t = blockIdx.x * 256 + threadIdx.x;    // 4096*256 threads
    int row = t >> 8;
    int col = (t & 255) << 2;
    float4 wv = *(const float4*)(Wx + ((size_t)row << 10) + col);
    float4 rv = *(const float4*)(Rh + ((size_t)row << 10) + col);
    bf16x4 wo = { (bf16)wv.x, (bf16)wv.y, (bf16)wv.z, (bf16)wv.w };
    bf16x4 ro = { (bf16)rv.x, (bf16)rv.y, (bf16)rv.z, (bf16)rv.w };
    *(bf16x4*)(W + ((size_t)row << 11) + col)        = wo;
    *(bf16x4*)(W + ((size_t)row << 11) + 1024 + col) = ro;
    if (t < 4096) bb[t] = bx[t] + bh[t];
}

// ---- fused GEMM (pre = U.W^T + bb) + LSTM elementwise epilogue ----
// Tile: 128 M x 128 N (N = 4 gates x 32 h-cols), BK=64, 256 threads = 4 waves.
// Wave w computes rows 32w..32w+31 x all 128 N -> holds all 4 gates per (b,h):
//   n = 16*ni + (lane&15); gate g = ni>>1; h_local = (ni&1)*16 + (lane&15).
__global__ __launch_bounds__(256, 2)
void lstm_fused(const bf16* __restrict__ U, const bf16* __restrict__ W,
                const float* __restrict__ bb, const float* __restrict__ cprev,
                float* __restrict__ out) {
    __shared__ __align__(16) bf16 As[128 * 64];
    __shared__ __align__(16) bf16 Bs[128 * 64];

    const int tid  = threadIdx.x;
    const int wave = tid >> 6;
    const int lane = tid & 63;
    const int quad = lane >> 4;
    const int lc   = lane & 15;

    // grouped swizzle: 8 m-tiles x 32 h-tiles per super-group keeps U+W hot in L2/L3
    int g   = blockIdx.x;
    int grp = g >> 8;
    int win = g & 255;
    int m_idx = (grp << 3) | (win & 7);   // 0..127
    int h_idx = win >> 3;                 // 0..31
    const int m0 = m_idx << 7;
    const int h0 = h_idx << 5;

    // per-lane bias preload (h depends only on lane&15)
    float bias[2][4];
#pragma unroll
    for (int hi = 0; hi < 2; ++hi)
#pragma unroll
        for (int gg = 0; gg < 4; ++gg)
            bias[hi][gg] = bb[(gg << 10) + h0 + (hi << 4) + lc];

    f32x4 acc[2][8];
#pragma unroll
    for (int mi = 0; mi < 2; ++mi)
#pragma unroll
        for (int ni = 0; ni < 8; ++ni)
            acc[mi][ni] = (f32x4){0.f, 0.f, 0.f, 0.f};

    const char* Ub = (const char*)U;   // row stride 4096 B
    const char* Wb = (const char*)W;   // row stride 4096 B

    for (int kb = 0; kb < K_DIM / 64; ++kb) {
        __syncthreads();   // previous iter's LDS reads done before overwrite
#pragma unroll
        for (int s = 0; s < 4; ++s) {
            int off  = (s << 12) + (tid << 4);      // byte offset in 16 KB tile
            int row  = off >> 7;                    // 128 B per tile row
            int colb = off & 127;
            int ldso = (s << 12) + (wave << 10);    // wave-uniform LDS base
            const char* ga = Ub + ((size_t)(m0 + row) << 12) + (kb << 7) + colb;
            g2l16(ga, (char*)As + ldso);
            int wrow = ((row >> 5) << 10) + h0 + (row & 31);  // gate-gathered W row
            const char* gb = Wb + ((size_t)wrow << 12) + (kb << 7) + colb;
            g2l16(gb, (char*)Bs + ldso);
        }
        __syncthreads();   // compiler drains vmcnt(0) here -> DMA complete

#pragma unroll
        for (int ks = 0; ks < 2; ++ks) {
            bf16x8 af[2];
            bf16x8 bfr[8];
#pragma unroll
            for (int mi = 0; mi < 2; ++mi)
                af[mi] = *(const bf16x8*)(As + ((wave << 5) + (mi << 4) + lc) * 64 + (ks << 5) + (quad << 3));
#pragma unroll
            for (int ni = 0; ni < 8; ++ni)
                bfr[ni] = *(const bf16x8*)(Bs + ((ni << 4) + lc) * 64 + (ks << 5) + (quad << 3));
#pragma unroll
            for (int mi = 0; mi < 2; ++mi)
#pragma unroll
                for (int ni = 0; ni < 8; ++ni)
                    acc[mi][ni] = __builtin_amdgcn_mfma_f32_16x16x32_bf16(
                        af[mi], bfr[ni], acc[mi][ni], 0, 0, 0);
        }
    }

    // epilogue: C/D layout col=lane&15, row=quad*4+reg (m89-verified)
    float* out_h = out;
    float* out_c = out + (size_t)B_DIM * H_DIM;
#pragma unroll
    for (int mi = 0; mi < 2; ++mi) {
#pragma unroll
        for (int r = 0; r < 4; ++r) {
            int brow  = m0 + (wave << 5) + (mi << 4) + (quad << 2) + r;
            size_t rb = (size_t)brow << 10;
#pragma unroll
            for (int hi = 0; hi < 2; ++hi) {
                int h = h0 + (hi << 4) + lc;
                float zp = acc[mi][0 + hi][r] + bias[hi][0];
                float ip = acc[mi][2 + hi][r] + bias[hi][1];
                float fp = acc[mi][4 + hi][r] + bias[hi][2];
                float op = acc[mi][6 + hi][r] + bias[hi][3];
                float zz = tanh_fast(zp);
                float ii = sigm_fast(ip);
                float ff = sigm_fast(fp);
                float oo = sigm_fast(op);
                float cp = cprev[rb + h];
                float cn = ff * cp + ii * zz;
                float hn = oo * tanh_fast(cn);
                out_h[rb + h] = hn;
                out_c[rb + h] = cn;
            }
        }
    }
}

extern "C" void kernel_launch(void* const* d_in, const int* in_sizes, int n_in,
                              void* d_out, int out_size, void* d_ws, size_t ws_size,
                              hipStream_t stream) {
    const float* x  = (const float*)d_in[0];
    const float* hp = (const float*)d_in[1];
    const float* cp = (const float*)d_in[2];
    const float* Wx = (const float*)d_in[3];
    const float* bx = (const float*)d_in[4];
    const float* Rh = (const float*)d_in[5];
    const float* bh = (const float*)d_in[6];

    // workspace layout (all 256B-aligned): U 64 MiB | W 16 MiB | bb 16 KiB
    bf16*  U  = (bf16*)d_ws;
    bf16*  W  = (bf16*)((char*)d_ws + (size_t)67108864);
    float* bb = (float*)((char*)d_ws + (size_t)67108864 + 16777216);

    cvt_xh<<<16384, 256, 0, stream>>>(x, hp, U);
    cvt_w <<< 4096, 256, 0, stream>>>(Wx, Rh, bx, bh, W, bb);
    lstm_fused<<<4096, 256, 0, stream>>>(U, W, bb, cp, (float*)d_out);
}

// Round 2
// 591.232 us; speedup vs baseline: 1.0516x; 1.0516x over previous
//
#include <hip/hip_runtime.h>
#include <stdint.h>

typedef __bf16 bf16;
typedef __bf16 bf16x8 __attribute__((ext_vector_type(8)));
typedef float  f32x4  __attribute__((ext_vector_type(4)));

#define B_DIM 16384
#define H_DIM 1024
#define K_DIM 2048   // I + H concatenated

// ---- async global->LDS, 16B per lane ----
__device__ __forceinline__ void g2l16(const void* g, void* l) {
    __builtin_amdgcn_global_load_lds(
        (const __attribute__((address_space(1))) void*)g,
        (__attribute__((address_space(3))) void*)l,
        16, 0, 0);
}

__device__ __forceinline__ float sigm_fast(float x) {
    x = fminf(fmaxf(x, -40.f), 40.f);
    float e = __builtin_amdgcn_exp2f(-1.4426950408889634f * x);
    return __builtin_amdgcn_rcpf(1.0f + e);
}
__device__ __forceinline__ float tanh_fast(float x) {
    x = fminf(fmaxf(x, -40.f), 40.f);
    float e = __builtin_amdgcn_exp2f(-2.8853900817779268f * x);   // exp(-2x)
    return (1.0f - e) * __builtin_amdgcn_rcpf(1.0f + e);
}

// ---- U bf16 [B, 2048]: U[b,0:1024]=x[b], U[b,1024:2048]=h_prev[b]
// grid-stride, 16B loads + 16B stores, 8 outputs/thread/iter
__global__ __launch_bounds__(256) void cvt_xh(const float* __restrict__ x,
                                              const float* __restrict__ h,
                                              bf16* __restrict__ U) {
    const int NCH = (B_DIM * K_DIM) / 8;           // bf16x8 chunks
    int stride = gridDim.x * 256;
    for (int i = blockIdx.x * 256 + threadIdx.x; i < NCH; i += stride) {
        int row = i >> 8;                          // 256 chunks per U row
        int c8  = i & 255;
        const float* src = (c8 < 128)
            ? (x + ((size_t)row << 10) + (c8 << 3))
            : (h + ((size_t)row << 10) + ((c8 - 128) << 3));
        float4 a = *(const float4*)src;
        float4 b = *(const float4*)(src + 4);
        bf16x8 o = { (bf16)a.x, (bf16)a.y, (bf16)a.z, (bf16)a.w,
                     (bf16)b.x, (bf16)b.y, (bf16)b.z, (bf16)b.w };
        *(bf16x8*)(U + ((size_t)i << 3)) = o;
    }
}

// ---- W bf16 [4096, 2048]: row g*1024+h = [Wx[g,h,:] | Rh[g,h,:]]; bb = bx+bh
__global__ __launch_bounds__(256) void cvt_w(const float* __restrict__ Wx,
                                             const float* __restrict__ Rh,
                                             const float* __restrict__ bx,
                                             const float* __restrict__ bh,
                                             bf16* __restrict__ W,
                                             float* __restrict__ bb) {
    const int NCH = (4096 * K_DIM) / 8;
    int t0 = blockIdx.x * 256 + threadIdx.x;
    int stride = gridDim.x * 256;
    for (int i = t0; i < NCH; i += stride) {
        int row = i >> 8;
        int c8  = i & 255;
        const float* src = (c8 < 128)
            ? (Wx + ((size_t)row << 10) + (c8 << 3))
            : (Rh + ((size_t)row << 10) + ((c8 - 128) << 3));
        float4 a = *(const float4*)src;
        float4 b = *(const float4*)(src + 4);
        bf16x8 o = { (bf16)a.x, (bf16)a.y, (bf16)a.z, (bf16)a.w,
                     (bf16)b.x, (bf16)b.y, (bf16)b.z, (bf16)b.w };
        *(bf16x8*)(W + ((size_t)i << 3)) = o;
    }
    if (t0 < 4096) bb[t0] = bx[t0] + bh[t0];
}

// ---- fused GEMM (pre = U.W^T + bb) + LSTM epilogue ----
// 128M x 128N tile, BK=64, 4 waves in 2x2: each wave 64M x 64N (4x4 frags).
// B tile row r -> gate (r>>4)&3, h_off (r>>6)*16 + (r&15)  => wave (wn) holds
// all 4 gates for h = h0 + wn*16 + lc  => epilogue needs no cross-lane traffic.
// LDS XOR swizzle: 16B chunk c of row r stored at chunk c^(r&7) (conflict-free
// b128 reads: 8 dwords/bank = minimum).
__global__ __launch_bounds__(256, 2)
void lstm_fused(const bf16* __restrict__ U, const bf16* __restrict__ W,
                const float* __restrict__ bb, const float* __restrict__ cprev,
                float* __restrict__ out) {
    __shared__ __align__(16) bf16 As[128 * 64];
    __shared__ __align__(16) bf16 Bs[128 * 64];

    const int tid  = threadIdx.x;
    const int wave = tid >> 6;
    const int lane = tid & 63;
    const int quad = lane >> 4;
    const int lc   = lane & 15;
    const int wm   = wave >> 1;
    const int wn   = wave & 1;

    // XCD-aware mapping: xcd = bid&7 owns h-slices {xcd, xcd+8, xcd+16, xcd+24},
    // sweeps all 128 m-tiles per slice (W slice 512 KB resident in its L2;
    // all XCDs sweep m in phase -> U tiles shared via L3).
    int bid   = blockIdx.x;
    int xcd   = bid & 7;
    int j     = bid >> 3;                  // 0..511
    int h_idx = xcd + ((j >> 7) << 3);     // 0..31
    int m_idx = j & 127;                   // 0..127
    const int m0 = m_idx << 7;
    const int h0 = h_idx << 5;

    // per-lane biases: gate g at h = h0 + wn*16 + lc
    float bias[4];
#pragma unroll
    for (int g = 0; g < 4; ++g)
        bias[g] = bb[(g << 10) + h0 + (wn << 4) + lc];

    f32x4 acc[4][4];
#pragma unroll
    for (int mi = 0; mi < 4; ++mi)
#pragma unroll
        for (int ni = 0; ni < 4; ++ni)
            acc[mi][ni] = (f32x4){0.f, 0.f, 0.f, 0.f};

    const char* Ub = (const char*)U;   // row stride 4096 B
    const char* Wb = (const char*)W;   // row stride 4096 B

    for (int kb = 0; kb < K_DIM / 64; ++kb) {
        __syncthreads();   // previous iter's LDS reads done before overwrite
#pragma unroll
        for (int s = 0; s < 4; ++s) {
            int slot  = (s << 8) + (wave << 6) + lane;   // 16B-chunk slot, 0..1023
            int row   = slot >> 3;                       // tile row 0..127
            int chunk = slot & 7;                        // LDS chunk position
            int colb  = (chunk ^ (row & 7)) << 4;        // swizzled global chunk
            int lb    = slot << 4;                       // = uniform base + lane*16
            const char* ga = Ub + ((size_t)(m0 + row) << 12) + (kb << 7) + colb;
            g2l16(ga, (char*)As + lb);
            int gate = (row >> 4) & 3;
            int hh   = ((row >> 6) << 4) + (row & 15);
            int wrow = (gate << 10) + h0 + hh;
            const char* gb = Wb + ((size_t)wrow << 12) + (kb << 7) + colb;
            g2l16(gb, (char*)Bs + lb);
        }
        __syncthreads();   // vmcnt(0) drain -> DMA complete

#pragma unroll
        for (int ks = 0; ks < 2; ++ks) {
            bf16x8 af[4];
            bf16x8 bfr[4];
#pragma unroll
            for (int mi = 0; mi < 4; ++mi) {
                int row = (wm << 6) + (mi << 4) + lc;
                int cs  = ((ks << 2) + quad) ^ (lc & 7);   // row&7 == lc&7
                af[mi]  = *(const bf16x8*)(As + (row << 6) + (cs << 3));
            }
#pragma unroll
            for (int ni = 0; ni < 4; ++ni) {
                int row = (wn << 6) + (ni << 4) + lc;
                int cs  = ((ks << 2) + quad) ^ (lc & 7);
                bfr[ni] = *(const bf16x8*)(Bs + (row << 6) + (cs << 3));
            }
#pragma unroll
            for (int mi = 0; mi < 4; ++mi)
#pragma unroll
                for (int ni = 0; ni < 4; ++ni)
                    acc[mi][ni] = __builtin_amdgcn_mfma_f32_16x16x32_bf16(
                        af[mi], bfr[ni], acc[mi][ni], 0, 0, 0);
        }
    }

    // epilogue: C/D layout col=lane&15, row=quad*4+reg; acc[mi][g] = gate g
    float* out_h = out;
    float* out_c = out + (size_t)B_DIM * H_DIM;
    const int h = h0 + (wn << 4) + lc;
#pragma unroll
    for (int mi = 0; mi < 4; ++mi) {
#pragma unroll
        for (int r = 0; r < 4; ++r) {
            int brow  = m0 + (wm << 6) + (mi << 4) + (quad << 2) + r;
            size_t rb = (size_t)brow << 10;
            float zp = acc[mi][0][r] + bias[0];
            float ip = acc[mi][1][r] + bias[1];
            float fp = acc[mi][2][r] + bias[2];
            float op = acc[mi][3][r] + bias[3];
            float zz = tanh_fast(zp);
            float ii = sigm_fast(ip);
            float ff = sigm_fast(fp);
            float oo = sigm_fast(op);
            float cp = cprev[rb + h];
            float cn = ff * cp + ii * zz;
            float hn = oo * tanh_fast(cn);
            out_h[rb + h] = hn;
            out_c[rb + h] = cn;
        }
    }
}

extern "C" void kernel_launch(void* const* d_in, const int* in_sizes, int n_in,
                              void* d_out, int out_size, void* d_ws, size_t ws_size,
                              hipStream_t stream) {
    const float* x  = (const float*)d_in[0];
    const float* hp = (const float*)d_in[1];
    const float* cp = (const float*)d_in[2];
    const float* Wx = (const float*)d_in[3];
    const float* bx = (const float*)d_in[4];
    const float* Rh = (const float*)d_in[5];
    const float* bh = (const float*)d_in[6];

    // workspace: U 64 MiB | W 16 MiB | bb 16 KiB
    bf16*  U  = (bf16*)d_ws;
    bf16*  W  = (bf16*)((char*)d_ws + (size_t)67108864);
    float* bb = (float*)((char*)d_ws + (size_t)67108864 + 16777216);

    cvt_xh<<<2048, 256, 0, stream>>>(x, hp, U);
    cvt_w <<<1024, 256, 0, stream>>>(Wx, Rh, bx, bh, W, bb);
    lstm_fused<<<4096, 256, 0, stream>>>(U, W, bb, cp, (float*)d_out);
}

// Round 4
// 580.219 us; speedup vs baseline: 1.0715x; 1.0190x over previous
//
#include <hip/hip_runtime.h>
#include <stdint.h>

typedef __bf16 bf16;
typedef __bf16 bf16x8 __attribute__((ext_vector_type(8)));
typedef float  f32x4  __attribute__((ext_vector_type(4)));
typedef float  fvec4  __attribute__((ext_vector_type(4)));   // clang-native for nontemporal builtin

#define B_DIM 16384
#define H_DIM 1024
#define K_DIM 2048   // I + H concatenated

// ---- async global->LDS, 16B per lane ----
__device__ __forceinline__ void g2l16(const void* g, void* l) {
    __builtin_amdgcn_global_load_lds(
        (const __attribute__((address_space(1))) void*)g,
        (__attribute__((address_space(3))) void*)l,
        16, 0, 0);
}

__device__ __forceinline__ float sigm_fast(float x) {
    x = fminf(fmaxf(x, -40.f), 40.f);
    float e = __builtin_amdgcn_exp2f(-1.4426950408889634f * x);
    return __builtin_amdgcn_rcpf(1.0f + e);
}
__device__ __forceinline__ float tanh_fast(float x) {
    x = fminf(fmaxf(x, -40.f), 40.f);
    float e = __builtin_amdgcn_exp2f(-2.8853900817779268f * x);   // exp(-2x)
    return (1.0f - e) * __builtin_amdgcn_rcpf(1.0f + e);
}

__device__ __forceinline__ bf16x8 cvt8(const float* __restrict__ src) {
    fvec4 a = __builtin_nontemporal_load((const fvec4*)src);
    fvec4 b = __builtin_nontemporal_load((const fvec4*)(src + 4));
    bf16x8 o = { (bf16)a.x, (bf16)a.y, (bf16)a.z, (bf16)a.w,
                 (bf16)b.x, (bf16)b.y, (bf16)b.z, (bf16)b.w };
    return o;
}

// ---- ONE streaming convert kernel, exact grid, 32B in / 16B out per thread.
// blocks [0,8192):      x  -> U[:, 0:1024]
// blocks [8192,16384):  h  -> U[:, 1024:2048]
// blocks [16384,20480): Wx/Rh -> W rows ([Wx[g,h,:] | Rh[g,h,:]]), + bb
__global__ __launch_bounds__(256) void cvt_all(const float* __restrict__ x,
                                               const float* __restrict__ h,
                                               const float* __restrict__ Wx,
                                               const float* __restrict__ Rh,
                                               const float* __restrict__ bx,
                                               const float* __restrict__ bh,
                                               bf16* __restrict__ U,
                                               bf16* __restrict__ W,
                                               float* __restrict__ bb) {
    int b = blockIdx.x;
    if (b < 16384) {
        // U halves: gid indexes 8-float chunks of a [16384 x 1024] fp32 matrix
        const float* src0 = (b < 8192) ? x : h;
        int half = (b < 8192) ? 0 : 1024;
        int gid  = (b & 8191) * 256 + threadIdx.x;   // 0 .. 2M-1
        int row  = gid >> 7;                          // 128 chunks per source row
        int c    = gid & 127;
        bf16x8 o = cvt8(src0 + ((size_t)row << 10) + (c << 3));
        *(bf16x8*)(U + ((size_t)row << 11) + half + (c << 3)) = o;
    } else {
        int gid = (b - 16384) * 256 + threadIdx.x;    // 0 .. 1M-1
        if (gid < 524288) {                           // Wx half
            int row = gid >> 7;
            int c   = gid & 127;
            bf16x8 o = cvt8(Wx + ((size_t)row << 10) + (c << 3));
            *(bf16x8*)(W + ((size_t)row << 11) + (c << 3)) = o;
        } else {                                      // Rh half
            int g2  = gid - 524288;
            int row = g2 >> 7;
            int c   = g2 & 127;
            bf16x8 o = cvt8(Rh + ((size_t)row << 10) + (c << 3));
            *(bf16x8*)(W + ((size_t)row << 11) + 1024 + (c << 3)) = o;
        }
        if (gid < 4096) bb[gid] = bx[gid] + bh[gid];
    }
}

// ---- fused GEMM (pre = U.W^T + bb) + LSTM epilogue ----
// 128M x 128N tile, BK=64, 4 waves in 2x2: each wave 64M x 64N (4x4 frags).
// B tile row r -> gate (r>>4)&3, h_off (r>>6)*16 + (r&15)  => wave (wn) holds
// all 4 gates for h = h0 + wn*16 + lc  => epilogue needs no cross-lane traffic.
// LDS XOR swizzle: 16B chunk c of row r stored at chunk c^(r&7) (conflict-free
// b128 reads; verified: SQ_LDS_BANK_CONFLICT == 0).
__global__ __launch_bounds__(256, 2)
void lstm_fused(const bf16* __restrict__ U, const bf16* __restrict__ W,
                const float* __restrict__ bb, const float* __restrict__ cprev,
                float* __restrict__ out) {
    __shared__ __align__(16) bf16 As[128 * 64];
    __shared__ __align__(16) bf16 Bs[128 * 64];

    const int tid  = threadIdx.x;
    const int wave = tid >> 6;
    const int lane = tid & 63;
    const int quad = lane >> 4;
    const int lc   = lane & 15;
    const int wm   = wave >> 1;
    const int wn   = wave & 1;

    // XCD-aware mapping: xcd = bid&7 owns h-slices {xcd, xcd+8, xcd+16, xcd+24},
    // sweeps all 128 m-tiles per slice; concurrent blocks (same j) share the
    // same U m-tile across XCDs -> L3 serves the re-reads.
    int bid   = blockIdx.x;
    int xcd   = bid & 7;
    int j     = bid >> 3;                  // 0..511
    int h_idx = xcd + ((j >> 7) << 3);     // 0..31
    int m_idx = j & 127;                   // 0..127
    const int m0 = m_idx << 7;
    const int h0 = h_idx << 5;

    // per-lane biases: gate g at h = h0 + wn*16 + lc
    float bias[4];
#pragma unroll
    for (int g = 0; g < 4; ++g)
        bias[g] = bb[(g << 10) + h0 + (wn << 4) + lc];

    f32x4 acc[4][4];
#pragma unroll
    for (int mi = 0; mi < 4; ++mi)
#pragma unroll
        for (int ni = 0; ni < 4; ++ni)
            acc[mi][ni] = (f32x4){0.f, 0.f, 0.f, 0.f};

    const char* Ub = (const char*)U;   // row stride 4096 B
    const char* Wb = (const char*)W;   // row stride 4096 B

    for (int kb = 0; kb < K_DIM / 64; ++kb) {
        __syncthreads();   // previous iter's LDS reads done before overwrite
#pragma unroll
        for (int s = 0; s < 4; ++s) {
            int slot  = (s << 8) + (wave << 6) + lane;   // 16B-chunk slot, 0..1023
            int row   = slot >> 3;                       // tile row 0..127
            int chunk = slot & 7;                        // LDS chunk position
            int colb  = (chunk ^ (row & 7)) << 4;        // swizzled global chunk
            int lb    = slot << 4;                       // = uniform base + lane*16
            const char* ga = Ub + ((size_t)(m0 + row) << 12) + (kb << 7) + colb;
            g2l16(ga, (char*)As + lb);
            int gate = (row >> 4) & 3;
            int hh   = ((row >> 6) << 4) + (row & 15);
            int wrow = (gate << 10) + h0 + hh;
            const char* gb = Wb + ((size_t)wrow << 12) + (kb << 7) + colb;
            g2l16(gb, (char*)Bs + lb);
        }
        __syncthreads();   // vmcnt(0) drain -> DMA complete

#pragma unroll
        for (int ks = 0; ks < 2; ++ks) {
            bf16x8 af[4];
            bf16x8 bfr[4];
#pragma unroll
            for (int mi = 0; mi < 4; ++mi) {
                int row = (wm << 6) + (mi << 4) + lc;
                int cs  = ((ks << 2) + quad) ^ (lc & 7);   // row&7 == lc&7
                af[mi]  = *(const bf16x8*)(As + (row << 6) + (cs << 3));
            }
#pragma unroll
            for (int ni = 0; ni < 4; ++ni) {
                int row = (wn << 6) + (ni << 4) + lc;
                int cs  = ((ks << 2) + quad) ^ (lc & 7);
                bfr[ni] = *(const bf16x8*)(Bs + (row << 6) + (cs << 3));
            }
#pragma unroll
            for (int mi = 0; mi < 4; ++mi)
#pragma unroll
                for (int ni = 0; ni < 4; ++ni)
                    acc[mi][ni] = __builtin_amdgcn_mfma_f32_16x16x32_bf16(
                        af[mi], bfr[ni], acc[mi][ni], 0, 0, 0);
        }
    }

    // epilogue: C/D layout col=lane&15, row=quad*4+reg; acc[mi][g] = gate g
    float* out_h = out;
    float* out_c = out + (size_t)B_DIM * H_DIM;
    const int h = h0 + (wn << 4) + lc;
#pragma unroll
    for (int mi = 0; mi < 4; ++mi) {
#pragma unroll
        for (int r = 0; r < 4; ++r) {
            int brow  = m0 + (wm << 6) + (mi << 4) + (quad << 2) + r;
            size_t rb = (size_t)brow << 10;
            float zp = acc[mi][0][r] + bias[0];
            float ip = acc[mi][1][r] + bias[1];
            float fp = acc[mi][2][r] + bias[2];
            float op = acc[mi][3][r] + bias[3];
            float zz = tanh_fast(zp);
            float ii = sigm_fast(ip);
            float ff = sigm_fast(fp);
            float oo = sigm_fast(op);
            float cp = cprev[rb + h];
            float cn = ff * cp + ii * zz;
            float hn = oo * tanh_fast(cn);
            out_h[rb + h] = hn;
            out_c[rb + h] = cn;
        }
    }
}

extern "C" void kernel_launch(void* const* d_in, const int* in_sizes, int n_in,
                              void* d_out, int out_size, void* d_ws, size_t ws_size,
                              hipStream_t stream) {
    const float* x  = (const float*)d_in[0];
    const float* hp = (const float*)d_in[1];
    const float* cp = (const float*)d_in[2];
    const float* Wx = (const float*)d_in[3];
    const float* bx = (const float*)d_in[4];
    const float* Rh = (const float*)d_in[5];
    const float* bh = (const float*)d_in[6];

    // workspace: U 64 MiB | W 16 MiB | bb 16 KiB
    bf16*  U  = (bf16*)d_ws;
    bf16*  W  = (bf16*)((char*)d_ws + (size_t)67108864);
    float* bb = (float*)((char*)d_ws + (size_t)67108864 + 16777216);

    cvt_all<<<20480, 256, 0, stream>>>(x, hp, Wx, Rh, bx, bh, U, W, bb);
    lstm_fused<<<4096, 256, 0, stream>>>(U, W, bb, cp, (float*)d_out);
}